// Round 7
// baseline (76.415 us; speedup 1.0000x reference)
//
#include <hip/hip_runtime.h>
#include <math.h>

// Multi-scale RoIAlign (FPN), fp32 — two-path hybrid, one template kernel
// instantiated twice (NARROW / wide), launched back-to-back; blocks early-exit
// on path mismatch (per-roi, wave-uniform, box-only test).
//
// NARROW (x-span <= 32 cols, ~80% of rois): stage 28 tap-rows x 32 cols per
// channel via 4x width-16 global_load_lds (ph-XOR swizzled source, linear LDS
// dest), double-buffered, counted vmcnt(4); 49 lanes read 16 swizzled taps.
// 5 VMEM instrs/channel vs 9 for gather (measured ~30 cyc/VMEM-instr flat).
//
// WIDE: R6's register gather (8x dwordx2 + packed LDS transpose), any W/H.

constexpr int CH = 256;
constexpr int POUT = 7;
constexpr int NSAMP = 14;            // POUT * SR
constexpr int NBIN = POUT * POUT;    // 49
constexpr int PER_ROI = CH * NBIN;   // 12544
constexpr int SROWS = 28;            // staged tap rows (q0,q1 per y-sample)
constexpr int SCOLS = 32;            // staged cols (8 granules of 4)
constexpr int CHBUF = 1024;          // padded floats per buffer (896 used)
constexpr int NWAVE = 2;
constexpr int CPW = 8;               // channels per wave
constexpr int CPB = NWAVE * CPW;     // 16
constexpr int NCG = CH / CPB;        // 16 blocks per roi

#define ASG __attribute__((address_space(1)))
#define ASL __attribute__((address_space(3)))

struct F2 { float x, y; };
__device__ inline F2 ld2(const float* p) {
    F2 v;
    __builtin_memcpy(&v, p, 8);
    return v;
}

template <bool NARROW>
__global__ __launch_bounds__(128)
void roi_kernel(const float* __restrict__ f0, const float* __restrict__ f1,
                const float* __restrict__ f2, const float* __restrict__ f3,
                const float* __restrict__ boxes, float* __restrict__ out, int K)
{
    constexpr int STAGEF = NARROW ? (NWAVE * 2 * CHBUF) : (NWAVE * 256);
    __shared__ alignas(16) float s_stage[STAGEF];
    __shared__ int   s_rowoff[SROWS];              // per-tap clamped row * W
    __shared__ float s_wy0[NSAMP], s_wy1[NSAMP];
    __shared__ int2  s_xrel[NSAMP];                // narrow: tap cols rel c0a
    __shared__ float s_wx0[NSAMP], s_wx1[NSAMP];
    __shared__ int   s_xlc[NSAMP];                 // wide: float2 col (<=W-2)
    __shared__ float s_ex0[NSAMP], s_ex1[NSAMP];   // wide: edge-folded x wts

    const int tid  = threadIdx.x;
    const int wave = tid >> 6;
    const int lane = tid & 63;
    const int roi  = blockIdx.x >> 4;              // NCG == 16
    const int cg   = blockIdx.x & (NCG - 1);
    const int b    = roi / K;

    const float bx1 = boxes[roi * 4 + 0], by1 = boxes[roi * 4 + 1];
    const float bx2 = boxes[roi * 4 + 2], by2 = boxes[roi * 4 + 3];

    const float area = (bx2 - bx1) * (by2 - by1);
    float lvlf = floorf(4.0f + log2f(sqrtf(area) / 224.0f + 1e-6f));
    lvlf = fminf(fmaxf(lvlf, 2.0f), 5.0f);
    const int lvl = (int)lvlf - 2;

    const float* feat; int H, W; float scale;
    if (lvl == 0)      { feat = f0; H = 200; W = 200; scale = 0.25f;    }
    else if (lvl == 1) { feat = f1; H = 100; W = 100; scale = 0.125f;   }
    else if (lvl == 2) { feat = f2; H = 50;  W = 50;  scale = 0.0625f;  }
    else               { feat = f3; H = 25;  W = 25;  scale = 0.03125f; }

    const float x1 = bx1 * scale, y1 = by1 * scale;
    const float rw = fmaxf(bx2 * scale - x1, 1.0f);
    const float rh = fmaxf(by2 * scale - y1, 1.0f);
    const float bw = rw * (1.0f / POUT);
    const float bh = rh * (1.0f / POUT);

    // Path decision from box only (identical FP expressions to the fill below).
    const float pc0f  = fminf(fmaxf(x1 + (0.5f * 0.5f) * bw, 0.0f), (float)(W - 1));
    const int   c0    = (int)floorf(pc0f);
    const int   c0a   = c0 & ~3;
    const float pc13f = fminf(fmaxf(x1 + (13.5f * 0.5f) * bw, 0.0f), (float)(W - 1));
    const int   q13   = min((int)floorf(pc13f) + 1, W - 1);
    const bool  isNarrow = ((W & 3) == 0) && (q13 - c0a <= SCOLS - 1);
    if (isNarrow != NARROW) return;

    if (tid < 2 * NSAMP) {
        const bool isY = tid < NSAMP;
        const int i = isY ? tid : tid - NSAMP;
        const float dim   = isY ? (float)H : (float)W;
        const float start = isY ? y1 : x1;
        const float bsz   = isY ? bh : bw;
        const float p = start + ((float)i + 0.5f) * 0.5f * bsz;
        const float valid = (p >= -1.0f && p <= dim) ? 1.0f : 0.0f;
        const float pc = fminf(fmaxf(p, 0.0f), dim - 1.0f);
        const int q0 = (int)floorf(pc);
        const float l = pc - (float)q0;
        const float w0 = (1.0f - l) * valid;
        const float w1 = l * valid;
        if (isY) {
            const int q1 = min(q0 + 1, (int)dim - 1);
            s_rowoff[2 * i]     = q0 * W;
            s_rowoff[2 * i + 1] = q1 * W;
            s_wy0[i] = w0;
            s_wy1[i] = w1;
        } else {
            const int q1 = min(q0 + 1, (int)dim - 1);
            s_xrel[i] = make_int2(min(max(q0 - c0a, 0), 63),
                                  min(max(q1 - c0a, 0), 63));
            s_wx0[i] = w0;
            s_wx1[i] = w1;
            const bool edge = (q0 > W - 2);
            s_xlc[i] = edge ? (W - 2) : q0;
            s_ex0[i] = edge ? 0.0f : w0;
            s_ex1[i] = edge ? (w1 + w0) : w1;
        }
    }
    __syncthreads();

    const int HW = H * W;
    const int cbase = cg * CPB + wave * CPW;
    const float* chan0 = feat + ((size_t)b * CH + cbase) * (size_t)HW;

    if constexpr (NARROW) {
        // ---- per-lane read state ----
        const int lp = (lane < NBIN) ? lane : (NBIN - 1);
        const int ph = lp / POUT, pw = lp - ph * POUT;
        const int2  xra = s_xrel[2 * pw], xrb = s_xrel[2 * pw + 1];
        const float wxa0 = s_wx0[2 * pw], wxa1 = s_wx1[2 * pw];
        const float wxb0 = s_wx0[2 * pw + 1], wxb1 = s_wx1[2 * pw + 1];
        const float wyA0 = s_wy0[2 * ph], wyA1 = s_wy1[2 * ph];
        const float wyB0 = s_wy0[2 * ph + 1], wyB1 = s_wy1[2 * ph + 1];

        // slot(col x, row group ph): 4*((x>>2)^ph) + (x&3)  (in [0,32))
        const int sa0 = 4 * ((xra.x >> 2) ^ ph) + (xra.x & 3);
        const int sa1 = 4 * ((xra.y >> 2) ^ ph) + (xra.y & 3);
        const int sb0 = 4 * ((xrb.x >> 2) ^ ph) + (xrb.x & 3);
        const int sb1 = 4 * ((xrb.y >> 2) ^ ph) + (xrb.y & 3);
        const int rbase = 4 * ph * SCOLS;

        // ---- staging source offsets (4 instrs x 64 lanes = 256 granules,
        // 224 real + 32 pad writes into CHBUF padding) ----
        int sidx[4];
        #pragma unroll
        for (int k = 0; k < 4; ++k) {
            const int s = 64 * k + lane;
            const int row = min(s >> 3, SROWS - 1);
            const int g = s & 7;
            sidx[k] = min(s_rowoff[row] + c0a + 4 * (g ^ (row >> 2)), HW - 4);
        }

        float* wstage = &s_stage[wave * 2 * CHBUF];
        const size_t obase = (size_t)roi * PER_ROI + (size_t)cbase * NBIN + lp;

#define STAGE(BUF, Q) do {                                                     \
    __builtin_amdgcn_sched_barrier(0);                                         \
    const float* ch_ = chan0 + (size_t)(Q) * HW;                               \
    ASL float* ld_ = (ASL float*)(wstage + (BUF) * CHBUF);                     \
    __builtin_amdgcn_global_load_lds((const ASG void*)(ch_ + sidx[0]),         \
                                     (ASL void*)(ld_ + 0 * 256), 16, 0, 0);    \
    __builtin_amdgcn_global_load_lds((const ASG void*)(ch_ + sidx[1]),         \
                                     (ASL void*)(ld_ + 1 * 256), 16, 0, 0);    \
    __builtin_amdgcn_global_load_lds((const ASG void*)(ch_ + sidx[2]),         \
                                     (ASL void*)(ld_ + 2 * 256), 16, 0, 0);    \
    __builtin_amdgcn_global_load_lds((const ASG void*)(ch_ + sidx[3]),         \
                                     (ASL void*)(ld_ + 3 * 256), 16, 0, 0);    \
} while (0)

#define WAITV(N) do {                                                          \
    asm volatile("s_waitcnt vmcnt(" #N ")" ::: "memory");                      \
    __builtin_amdgcn_sched_barrier(0);                                         \
} while (0)

#define COMPUTE(BUF, Q) do {                                                   \
    const float* rp_ = wstage + (BUF) * CHBUF + rbase;                         \
    const float t00 = rp_[0 * SCOLS + sa0], t01 = rp_[0 * SCOLS + sa1];        \
    const float t02 = rp_[0 * SCOLS + sb0], t03 = rp_[0 * SCOLS + sb1];        \
    const float t10 = rp_[1 * SCOLS + sa0], t11 = rp_[1 * SCOLS + sa1];        \
    const float t12 = rp_[1 * SCOLS + sb0], t13 = rp_[1 * SCOLS + sb1];        \
    const float t20 = rp_[2 * SCOLS + sa0], t21 = rp_[2 * SCOLS + sa1];        \
    const float t22 = rp_[2 * SCOLS + sb0], t23 = rp_[2 * SCOLS + sb1];        \
    const float t30 = rp_[3 * SCOLS + sa0], t31 = rp_[3 * SCOLS + sa1];        \
    const float t32 = rp_[3 * SCOLS + sb0], t33 = rp_[3 * SCOLS + sb1];        \
    const float acc_ =                                                         \
          wyA0 * (wxa0 * t00 + wxa1 * t01 + wxb0 * t02 + wxb1 * t03)           \
        + wyA1 * (wxa0 * t10 + wxa1 * t11 + wxb0 * t12 + wxb1 * t13)           \
        + wyB0 * (wxa0 * t20 + wxa1 * t21 + wxb0 * t22 + wxb1 * t23)           \
        + wyB1 * (wxa0 * t30 + wxa1 * t31 + wxb0 * t32 + wxb1 * t33);          \
    if (lane < NBIN) out[obase + (Q) * NBIN] = acc_ * 0.25f;                   \
} while (0)

        STAGE(0, 0);
        STAGE(1, 1);
        WAITV(4); COMPUTE(0, 0); STAGE(0, 2);
        WAITV(4); COMPUTE(1, 1); STAGE(1, 3);
        WAITV(4); COMPUTE(0, 2); STAGE(0, 4);
        WAITV(4); COMPUTE(1, 3); STAGE(1, 5);
        WAITV(4); COMPUTE(0, 4); STAGE(0, 6);
        WAITV(4); COMPUTE(1, 5); STAGE(1, 7);
        WAITV(4); COMPUTE(0, 6);
        WAITV(0); COMPUTE(1, 7);
#undef STAGE
#undef WAITV
#undef COMPUTE
    } else {
        // -------- WIDE: R6 register gather --------
        const int  ly   = lane / 14;
        const int  sx0  = lane - 14 * ly;
        const bool lact = (lane < 56);
        const int  sxc  = lact ? sx0 : 0;
        const int  xoff = s_xlc[sxc];
        const float e0  = s_ex0[sxc], e1 = s_ex1[sxc];

        int   offA[4], offB[4], wb[4];
        float wy0q[4], wy1q[4];
        bool  act[4];
        #pragma unroll
        for (int q = 0; q < 4; ++q) {
            const int  sy = 4 * q + ly;
            const bool a  = lact && (sy < NSAMP);
            act[q] = a;
            const int syc = a ? sy : 0;
            offA[q] = s_rowoff[2 * syc]     + xoff;
            offB[q] = s_rowoff[2 * syc + 1] + xoff;
            wy0q[q] = s_wy0[syc];
            wy1q[q] = s_wy1[syc];
            wb[q]   = 4 * ((sy >> 1) * POUT + (sxc >> 1)) + 2 * (sy & 1) + (sxc & 1);
        }

        float* sw = &s_stage[wave * 256];
        const size_t obase = (size_t)roi * PER_ROI + (size_t)cbase * NBIN + lane;

        F2 cA[4], cB[4], nA[4], nB[4];
        #pragma unroll
        for (int q = 0; q < 4; ++q) {
            cA[q] = ld2(chan0 + offA[q]);
            cB[q] = ld2(chan0 + offB[q]);
        }

        #pragma unroll
        for (int c = 0; c < CPW; ++c) {
            if (c + 1 < CPW) {
                const float* ch = chan0 + (size_t)(c + 1) * HW;
                #pragma unroll
                for (int q = 0; q < 4; ++q) {
                    nA[q] = ld2(ch + offA[q]);
                    nB[q] = ld2(ch + offB[q]);
                }
            }

            #pragma unroll
            for (int q = 0; q < 4; ++q) {
                const float sv = wy0q[q] * (e0 * cA[q].x + e1 * cA[q].y)
                               + wy1q[q] * (e0 * cB[q].x + e1 * cB[q].y);
                if (act[q]) sw[wb[q]] = sv;
            }

            asm volatile("s_waitcnt lgkmcnt(0)" ::: "memory");
            __builtin_amdgcn_sched_barrier(0);

            const float4 v = *(const float4*)(sw + 4 * lane);
            const float o = (v.x + v.y + v.z + v.w) * 0.25f;
            if (lane < NBIN) out[obase + (size_t)c * NBIN] = o;

            #pragma unroll
            for (int q = 0; q < 4; ++q) { cA[q] = nA[q]; cB[q] = nB[q]; }
        }
    }
}

extern "C" void kernel_launch(void* const* d_in, const int* in_sizes, int n_in,
                              void* d_out, int out_size, void* d_ws, size_t ws_size,
                              hipStream_t stream) {
    const float* f0    = (const float*)d_in[0];
    const float* f1    = (const float*)d_in[1];
    const float* f2    = (const float*)d_in[2];
    const float* f3    = (const float*)d_in[3];
    const float* boxes = (const float*)d_in[4];
    float* out = (float*)d_out;

    const int B    = in_sizes[0] / (256 * 200 * 200);
    const int nroi = in_sizes[4] / 4;
    const int K    = nroi / B;

    roi_kernel<true><<<nroi * NCG, 128, 0, stream>>>(f0, f1, f2, f3, boxes, out, K);
    roi_kernel<false><<<nroi * NCG, 128, 0, stream>>>(f0, f1, f2, f3, boxes, out, K);
}

// Round 8
// 64.079 us; speedup vs baseline: 1.1925x; 1.1925x over previous
//
#include <hip/hip_runtime.h>
#include <math.h>

// Multi-scale RoIAlign (FPN), fp32 — bin-major register-only gather.
// Block = (roi, 16 channels), 2 waves x 8 channels. Lane = output bin (49/64).
// Per channel per lane: 4 tap-rows; NARROW rois (x-taps of both x-samples fit
// in 4 consecutive cols, i.e. bw<=4 — all level-1 + most level-0 rois): one
// unaligned float4 per row + channel-invariant 4-weight dot (both x-interps
// folded) -> 4 loads + 1 store = 5 VMEM instrs, ZERO LDS in the loop.
// WIDE rois: 2 float2 per row (8 loads), same epilogue. Single dispatch,
// block-uniform branch. Register double-buffer across the 8-channel loop.

constexpr int CH = 256;
constexpr int POUT = 7;
constexpr int NSAMP = 14;           // POUT * SR
constexpr int NBIN = POUT * POUT;   // 49
constexpr int PER_ROI = CH * NBIN;  // 12544
constexpr int NWAVE = 2;
constexpr int CPW = 8;              // channels per wave
constexpr int CPB = NWAVE * CPW;    // 16 channels per block
constexpr int NCG = CH / CPB;       // 16 blocks per roi

struct F2 { float x, y; };
__device__ inline F2 ld2(const float* p) { F2 v; __builtin_memcpy(&v, p, 8); return v; }
struct F4 { float x, y, z, w; };
__device__ inline F4 ld4(const float* p) { F4 v; __builtin_memcpy(&v, p, 16); return v; }

__global__ __launch_bounds__(128)
void roi_align_bin_kernel(const float* __restrict__ f0,
                          const float* __restrict__ f1,
                          const float* __restrict__ f2,
                          const float* __restrict__ f3,
                          const float* __restrict__ boxes,
                          float* __restrict__ out,
                          int K)
{
    __shared__ int   s_rowoff[2 * NSAMP];          // per-tap clamped row * W
    __shared__ float s_wy0[NSAMP], s_wy1[NSAMP];   // y weights (validity folded)
    __shared__ int   s_xlc[NSAMP];                 // x float2 col (<= W-2), edge-folded
    __shared__ float s_ex0[NSAMP], s_ex1[NSAMP];   // x weights, edge+validity folded

    const int tid  = threadIdx.x;
    const int wave = tid >> 6;
    const int lane = tid & 63;
    const int roi  = blockIdx.x >> 4;              // NCG == 16
    const int cg   = blockIdx.x & (NCG - 1);
    const int b    = roi / K;

    const float bx1 = boxes[roi * 4 + 0], by1 = boxes[roi * 4 + 1];
    const float bx2 = boxes[roi * 4 + 2], by2 = boxes[roi * 4 + 3];

    const float area = (bx2 - bx1) * (by2 - by1);
    float lvlf = floorf(4.0f + log2f(sqrtf(area) / 224.0f + 1e-6f));
    lvlf = fminf(fmaxf(lvlf, 2.0f), 5.0f);
    const int lvl = (int)lvlf - 2;

    const float* feat; int H, W; float scale;
    if (lvl == 0)      { feat = f0; H = 200; W = 200; scale = 0.25f;    }
    else if (lvl == 1) { feat = f1; H = 100; W = 100; scale = 0.125f;   }
    else if (lvl == 2) { feat = f2; H = 50;  W = 50;  scale = 0.0625f;  }
    else               { feat = f3; H = 25;  W = 25;  scale = 0.03125f; }

    const float x1 = bx1 * scale, y1 = by1 * scale;
    const float rw = fmaxf(bx2 * scale - x1, 1.0f);
    const float rh = fmaxf(by2 * scale - y1, 1.0f);
    const float bw = rw * (1.0f / POUT);
    const float bh = rh * (1.0f / POUT);

    if (tid < 2 * NSAMP) {
        const bool isY = tid < NSAMP;
        const int i = isY ? tid : tid - NSAMP;
        const float dim   = isY ? (float)H : (float)W;
        const float start = isY ? y1 : x1;
        const float bsz   = isY ? bh : bw;
        const float p = start + ((float)i + 0.5f) * 0.5f * bsz;
        const float valid = (p >= -1.0f && p <= dim) ? 1.0f : 0.0f;
        const float pc = fminf(fmaxf(p, 0.0f), dim - 1.0f);
        const int q0 = (int)floorf(pc);
        const float l = pc - (float)q0;
        const float w0 = (1.0f - l) * valid;
        const float w1 = l * valid;
        if (isY) {
            const int q1 = min(q0 + 1, (int)dim - 1);
            s_rowoff[2 * i]     = q0 * W;
            s_rowoff[2 * i + 1] = q1 * W;
            s_wy0[i] = w0;
            s_wy1[i] = w1;
        } else {
            // float2 at col lc covers (lc, lc+1). If q0==W-1, fold w0 onto .y.
            const bool edge = (q0 > W - 2);
            s_xlc[i] = edge ? (W - 2) : q0;
            s_ex0[i] = edge ? 0.0f : w0;
            s_ex1[i] = edge ? (w1 + w0) : w1;
        }
    }
    __syncthreads();

    // Block-uniform path decision: both x-samples of every bin must fit a
    // 4-col window (lc spacing <= 2).
    bool narrow = true;
    #pragma unroll
    for (int j = 0; j < POUT; ++j)
        narrow = narrow && (s_xlc[2 * j + 1] - s_xlc[2 * j] <= 2);

    // ---- per-lane (bin) channel-invariant state ----
    const int  lp = (lane < NBIN) ? lane : (NBIN - 1);
    const bool act = (lane < NBIN);
    const int  by = lp / POUT, bx = lp - POUT * by;

    const int ro0 = s_rowoff[4 * by + 0];   // sample 2by   tap rows
    const int ro1 = s_rowoff[4 * by + 1];
    const int ro2 = s_rowoff[4 * by + 2];   // sample 2by+1 tap rows
    const int ro3 = s_rowoff[4 * by + 3];
    const float wy0 = s_wy0[2 * by],     wy1 = s_wy1[2 * by];
    const float wy2 = s_wy0[2 * by + 1], wy3 = s_wy1[2 * by + 1];

    const int lc0 = s_xlc[2 * bx], lc1 = s_xlc[2 * bx + 1];
    const float e00 = s_ex0[2 * bx],     e01 = s_ex1[2 * bx];
    const float e10 = s_ex0[2 * bx + 1], e11 = s_ex1[2 * bx + 1];

    const int HW = H * W;
    const int cbase = cg * CPB + wave * CPW;
    const float* chan0 = feat + ((size_t)b * CH + cbase) * (size_t)HW;
    const size_t obase = (size_t)roi * PER_ROI + (size_t)cbase * NBIN + lp;

    if (narrow) {
        // float4 window [base, base+3] covers taps (lc0,lc0+1,lc1,lc1+1).
        const int base = min(lc0, W - 4);
        const int i0 = lc0 - base;          // 0..2 (>0 only at right edge)
        const int i1 = lc1 - base;          // i0..2
        // Fold both x-interps into one 4-weight vector (channel-invariant).
        const float w40 = (i0 == 0 ? e00 : 0.0f) + (i1 == 0 ? e10 : 0.0f);
        const float w41 = (i0 == 1 ? e00 : 0.0f) + (i0 == 0 ? e01 : 0.0f)
                        + (i1 == 1 ? e10 : 0.0f) + (i1 == 0 ? e11 : 0.0f);
        const float w42 = (i0 == 2 ? e00 : 0.0f) + (i0 == 1 ? e01 : 0.0f)
                        + (i1 == 2 ? e10 : 0.0f) + (i1 == 1 ? e11 : 0.0f);
        const float w43 = (i0 == 2 ? e01 : 0.0f) + (i1 == 2 ? e11 : 0.0f);

        F4 v0 = ld4(chan0 + ro0 + base);
        F4 v1 = ld4(chan0 + ro1 + base);
        F4 v2 = ld4(chan0 + ro2 + base);
        F4 v3 = ld4(chan0 + ro3 + base);

        #pragma unroll
        for (int c = 0; c < CPW; ++c) {
            F4 n0, n1, n2, n3;
            if (c + 1 < CPW) {
                const float* ch = chan0 + (size_t)(c + 1) * HW;
                n0 = ld4(ch + ro0 + base);
                n1 = ld4(ch + ro1 + base);
                n2 = ld4(ch + ro2 + base);
                n3 = ld4(ch + ro3 + base);
            }
            const float rv0 = v0.x * w40 + v0.y * w41 + v0.z * w42 + v0.w * w43;
            const float rv1 = v1.x * w40 + v1.y * w41 + v1.z * w42 + v1.w * w43;
            const float rv2 = v2.x * w40 + v2.y * w41 + v2.z * w42 + v2.w * w43;
            const float rv3 = v3.x * w40 + v3.y * w41 + v3.z * w42 + v3.w * w43;
            const float acc = wy0 * rv0 + wy1 * rv1 + wy2 * rv2 + wy3 * rv3;
            if (act) out[obase + (size_t)c * NBIN] = acc * 0.25f;
            v0 = n0; v1 = n1; v2 = n2; v3 = n3;
        }
    } else {
        // WIDE: two float2 per tap-row (x-taps far apart).
        F2 a0 = ld2(chan0 + ro0 + lc0), d0 = ld2(chan0 + ro0 + lc1);
        F2 a1 = ld2(chan0 + ro1 + lc0), d1 = ld2(chan0 + ro1 + lc1);
        F2 a2 = ld2(chan0 + ro2 + lc0), d2 = ld2(chan0 + ro2 + lc1);
        F2 a3 = ld2(chan0 + ro3 + lc0), d3 = ld2(chan0 + ro3 + lc1);

        #pragma unroll
        for (int c = 0; c < CPW; ++c) {
            F2 na0, na1, na2, na3, nd0, nd1, nd2, nd3;
            if (c + 1 < CPW) {
                const float* ch = chan0 + (size_t)(c + 1) * HW;
                na0 = ld2(ch + ro0 + lc0); nd0 = ld2(ch + ro0 + lc1);
                na1 = ld2(ch + ro1 + lc0); nd1 = ld2(ch + ro1 + lc1);
                na2 = ld2(ch + ro2 + lc0); nd2 = ld2(ch + ro2 + lc1);
                na3 = ld2(ch + ro3 + lc0); nd3 = ld2(ch + ro3 + lc1);
            }
            const float rv0 = e00 * a0.x + e01 * a0.y + e10 * d0.x + e11 * d0.y;
            const float rv1 = e00 * a1.x + e01 * a1.y + e10 * d1.x + e11 * d1.y;
            const float rv2 = e00 * a2.x + e01 * a2.y + e10 * d2.x + e11 * d2.y;
            const float rv3 = e00 * a3.x + e01 * a3.y + e10 * d3.x + e11 * d3.y;
            const float acc = wy0 * rv0 + wy1 * rv1 + wy2 * rv2 + wy3 * rv3;
            if (act) out[obase + (size_t)c * NBIN] = acc * 0.25f;
            a0 = na0; a1 = na1; a2 = na2; a3 = na3;
            d0 = nd0; d1 = nd1; d2 = nd2; d3 = nd3;
        }
    }
}

extern "C" void kernel_launch(void* const* d_in, const int* in_sizes, int n_in,
                              void* d_out, int out_size, void* d_ws, size_t ws_size,
                              hipStream_t stream) {
    const float* f0    = (const float*)d_in[0];
    const float* f1    = (const float*)d_in[1];
    const float* f2    = (const float*)d_in[2];
    const float* f3    = (const float*)d_in[3];
    const float* boxes = (const float*)d_in[4];
    float* out = (float*)d_out;

    const int B    = in_sizes[0] / (256 * 200 * 200);
    const int nroi = in_sizes[4] / 4;
    const int K    = nroi / B;

    roi_align_bin_kernel<<<nroi * NCG, 128, 0, stream>>>(f0, f1, f2, f3, boxes, out, K);
}